// Round 1
// baseline (2446.222 us; speedup 1.0000x reference)
//
#include <hip/hip_runtime.h>
#include <math.h>

#define B_   32
#define K_   2048
#define C_   256
#define P_   256
#define S_   16
#define OUTC 119

// output offsets (floats)
#define OFF0 0        // obj        (B,P,2)
#define OFF1 16384    // center     (B,P,3)
#define OFF2 40960    // size_scores(B,P,18)
#define OFF3 188416   // size_res   (B,P,18,3)
#define OFF4 630784   // pred_size  (B,P,3)
#define OFF5 655360   // sem        (B,P,18)
#define OFF6 802816   // corners    (B,P,8,3)
#define OFF7 999424   // sem_logits (B,P,19)
#define OFF8 1155072  // obj_prob   (B,P)
#define OFF9 1163264  // sem_prob   (B,P,18)

__device__ __forceinline__ float sqdist_rn(float ax, float ay, float az,
                                           float bx, float by, float bz) {
  // numpy order: ((dx*dx + dy*dy) + dz*dz), no FMA contraction
  float dx = __fsub_rn(ax, bx), dy = __fsub_rn(ay, by), dz = __fsub_rn(az, bz);
  return __fadd_rn(__fadd_rn(__fmul_rn(dx, dx), __fmul_rn(dy, dy)),
                   __fmul_rn(dz, dz));
}

// ---------------------------------------------------------------- FPS ------
__global__ __launch_bounds__(256) void fps_kernel(const float* __restrict__ xyz,
                                                  float* __restrict__ new_xyz) {
  const int b = blockIdx.x, t = threadIdx.x;
  const float* xb = xyz + b * K_ * 3;
  float px[8], py[8], pz[8], dist[8];
#pragma unroll
  for (int j = 0; j < 8; j++) {
    int k = t + 256 * j;
    px[j] = xb[3 * k + 0];
    py[j] = xb[3 * k + 1];
    pz[j] = xb[3 * k + 2];
    dist[j] = 1e10f;
  }
  __shared__ float s_val[4];
  __shared__ int s_idx[4];
  __shared__ int s_far;
  int far = 0;
  for (int i = 0; i < P_; i++) {
    float cx = xb[3 * far + 0], cy = xb[3 * far + 1], cz = xb[3 * far + 2];
    if (t == 0) {
      float* nx = new_xyz + (b * P_ + i) * 3;
      nx[0] = cx; nx[1] = cy; nx[2] = cz;
    }
    float bv = -1.0f;
    int bk = 0x7fffffff;
#pragma unroll
    for (int j = 0; j < 8; j++) {
      float d = sqdist_rn(px[j], py[j], pz[j], cx, cy, cz);
      dist[j] = fminf(dist[j], d);
      int k = t + 256 * j;
      if (dist[j] > bv || (dist[j] == bv && k < bk)) { bv = dist[j]; bk = k; }
    }
#pragma unroll
    for (int off = 32; off >= 1; off >>= 1) {
      float ov = __shfl_down(bv, off);
      int ok = __shfl_down(bk, off);
      if (ov > bv || (ov == bv && ok < bk)) { bv = ov; bk = ok; }
    }
    if ((t & 63) == 0) { s_val[t >> 6] = bv; s_idx[t >> 6] = bk; }
    __syncthreads();
    if (t == 0) {
      for (int w = 1; w < 4; w++) {
        float ov = s_val[w]; int ok = s_idx[w];
        if (ov > bv || (ov == bv && ok < bk)) { bv = ov; bk = ok; }
      }
      s_far = bk;
    }
    __syncthreads();
    far = s_far;
  }
}

// ---------------------------------------------------------- ball query -----
__global__ __launch_bounds__(256) void ballq_kernel(const float* __restrict__ xyz,
                                                    const float* __restrict__ new_xyz,
                                                    int* __restrict__ idxw) {
  const int b = blockIdx.x, t = threadIdx.x;
  __shared__ __align__(16) float pts[K_ * 4];
  const float* xb = xyz + b * K_ * 3;
#pragma unroll
  for (int j = 0; j < 8; j++) {
    int k = t + 256 * j;
    pts[4 * k + 0] = xb[3 * k + 0];
    pts[4 * k + 1] = xb[3 * k + 1];
    pts[4 * k + 2] = xb[3 * k + 2];
    pts[4 * k + 3] = 0.f;
  }
  __syncthreads();
  const float r2 = (float)(0.3 * 0.3);
  const int p = t;
  const float nx = new_xyz[(b * P_ + p) * 3 + 0];
  const float ny = new_xyz[(b * P_ + p) * 3 + 1];
  const float nz = new_xyz[(b * P_ + p) * 3 + 2];
  int* ob = idxw + (b * P_ + p) * S_;
  int cnt = 0, first = 0;
  for (int k = 0; k < K_; k++) {
    if (cnt >= S_) break;
    const float4 q = *(const float4*)&pts[4 * k];
    float d2 = sqdist_rn(q.x, q.y, q.z, nx, ny, nz);
    if (d2 < r2) {
      if (cnt == 0) first = k;
      ob[cnt] = k;
      cnt++;
    }
  }
  for (int s = cnt; s < S_; s++) ob[s] = first;
}

// ------------------------------------------------------------- SA MLP ------
// one block per (b,p): gather 16x259 input, 3 conv layers + BN + ReLU, maxpool
#define SAST 288  // padded row stride (259 valid + zeros to 288 = 18 tiles of 16)
__global__ __launch_bounds__(256, 2) void sa_kernel(
    const float* __restrict__ xyz, const float* __restrict__ features,
    const float* __restrict__ w1, const float* __restrict__ w2,
    const float* __restrict__ w3, const float* __restrict__ gma,
    const float* __restrict__ bta, const float* __restrict__ mu,
    const float* __restrict__ var, const float* __restrict__ new_xyz,
    const int* __restrict__ idxw, float* __restrict__ y) {
  const int blk = blockIdx.x;
  const int b = blk >> 8, p = blk & 255, t = threadIdx.x;
  __shared__ __align__(16) float bufA[S_ * SAST];
  __shared__ __align__(16) float bufB[S_ * SAST];
  __shared__ __align__(16) float Wt[256 * 20];
  __shared__ int k_sh[S_];
  __shared__ float redM[2 * 256];

  const float* xb = xyz + b * K_ * 3;
  // gather xyz part + indices
  if (t < 16) {
    int k = idxw[(b * P_ + p) * S_ + t];
    k_sh[t] = k;
    float nx = new_xyz[(b * P_ + p) * 3 + 0];
    float ny = new_xyz[(b * P_ + p) * 3 + 1];
    float nz = new_xyz[(b * P_ + p) * 3 + 2];
    bufA[t * SAST + 0] = (xb[3 * k + 0] - nx) / 0.3f;
    bufA[t * SAST + 1] = (xb[3 * k + 1] - ny) / 0.3f;
    bufA[t * SAST + 2] = (xb[3 * k + 2] - nz) / 0.3f;
  }
  // zero pad c in [259,288)
  for (int u = t; u < 16 * 29; u += 256) {
    int s = u / 29;
    int c = 259 + (u - 29 * s);
    bufA[s * SAST + c] = 0.f;
  }
  __syncthreads();
  // gather features: thread t = channel t
  const float* fb = features + b * C_ * K_;
#pragma unroll
  for (int s = 0; s < 16; s++) bufA[s * SAST + 3 + t] = fb[t * K_ + k_sh[s]];
  __syncthreads();

  const int oA = t & 127, oB = oA + 128, sBase = (t >> 7) * 8;
  float accA[8], accB[8];

  for (int l = 0; l < 3; l++) {
    const float* w = (l == 0) ? w1 : ((l == 1) ? w2 : w3);
    const float* inb = (l == 1) ? bufB : bufA;
    float* outb = (l == 0) ? bufB : bufA;
    const int ntile = (l == 0) ? 18 : 16;
#pragma unroll
    for (int ss = 0; ss < 8; ss++) { accA[ss] = 0.f; accB[ss] = 0.f; }
    for (int tile = 0; tile < ntile; tile++) {
      const int c0 = tile * 16;
      // stage weight tile 256x16 into LDS (rows padded to 20)
      {
        const int orow = t >> 2, q = t & 3;
        const int c = c0 + q * 4;
#pragma unroll
        for (int pass = 0; pass < 4; pass++) {
          int oo = orow + pass * 64;
          float4 v;
          if (l == 0) {
            v.x = (c + 0 < 259) ? w[oo * 259 + c + 0] : 0.f;
            v.y = (c + 1 < 259) ? w[oo * 259 + c + 1] : 0.f;
            v.z = (c + 2 < 259) ? w[oo * 259 + c + 2] : 0.f;
            v.w = (c + 3 < 259) ? w[oo * 259 + c + 3] : 0.f;
          } else {
            v = *(const float4*)(w + oo * 256 + c);
          }
          *(float4*)&Wt[oo * 20 + q * 4] = v;
        }
      }
      __syncthreads();
#pragma unroll
      for (int j4 = 0; j4 < 4; j4++) {
        const float4 wa = *(const float4*)&Wt[oA * 20 + j4 * 4];
        const float4 wb = *(const float4*)&Wt[oB * 20 + j4 * 4];
#pragma unroll
        for (int ss = 0; ss < 8; ss++) {
          const float4 xv =
              *(const float4*)&inb[(sBase + ss) * SAST + c0 + j4 * 4];
          accA[ss] = fmaf(wa.x, xv.x, accA[ss]);
          accA[ss] = fmaf(wa.y, xv.y, accA[ss]);
          accA[ss] = fmaf(wa.z, xv.z, accA[ss]);
          accA[ss] = fmaf(wa.w, xv.w, accA[ss]);
          accB[ss] = fmaf(wb.x, xv.x, accB[ss]);
          accB[ss] = fmaf(wb.y, xv.y, accB[ss]);
          accB[ss] = fmaf(wb.z, xv.z, accB[ss]);
          accB[ss] = fmaf(wb.w, xv.w, accB[ss]);
        }
      }
      __syncthreads();
    }
    if (l < 2) {
      const float sA = gma[l * 256 + oA] / sqrtf(var[l * 256 + oA] + 1e-5f);
      const float sB = gma[l * 256 + oB] / sqrtf(var[l * 256 + oB] + 1e-5f);
      const float mA = mu[l * 256 + oA], mB = mu[l * 256 + oB];
      const float bA = bta[l * 256 + oA], bB = bta[l * 256 + oB];
#pragma unroll
      for (int ss = 0; ss < 8; ss++) {
        outb[(sBase + ss) * SAST + oA] = fmaxf((accA[ss] - mA) * sA + bA, 0.f);
        outb[(sBase + ss) * SAST + oB] = fmaxf((accB[ss] - mB) * sB + bB, 0.f);
      }
      // visibility guaranteed by the next layer's first post-staging barrier
    } else {
      // maxpool over samples; BN+ReLU after max (valid: scale > 0, monotone)
      float ra = accA[0], rb = accB[0];
#pragma unroll
      for (int ss = 1; ss < 8; ss++) {
        ra = fmaxf(ra, accA[ss]);
        rb = fmaxf(rb, accB[ss]);
      }
      const int h = t >> 7;
      redM[h * 256 + oA] = ra;
      redM[h * 256 + oB] = rb;
      __syncthreads();
      const float raw = fmaxf(redM[t], redM[256 + t]);
      const float sc = gma[512 + t] / sqrtf(var[512 + t] + 1e-5f);
      const float val = fmaxf((raw - mu[512 + t]) * sc + bta[512 + t], 0.f);
      y[(b * P_ + p) * 256 + t] = val;
    }
  }
}

// ------------------------------------------------- P-layers + all heads ----
#define PHST 260
__global__ __launch_bounds__(256, 2) void phead_kernel(
    const float* __restrict__ y, const float* __restrict__ pw1,
    const float* __restrict__ pw2, const float* __restrict__ pw3,
    const float* __restrict__ pb3, const float* __restrict__ pg,
    const float* __restrict__ pb, const float* __restrict__ pm,
    const float* __restrict__ pv, const float* __restrict__ new_xyz,
    const float* __restrict__ msa, float* __restrict__ out) {
  const int blk = blockIdx.x;
  const int b = blk >> 4, p0 = (blk & 15) * 16, t = threadIdx.x;
  __shared__ __align__(16) float Yt[16 * PHST];
  __shared__ __align__(16) float Ht[16 * PHST];
  __shared__ __align__(16) float Wt[256 * 20];
  __shared__ float net_s[16 * 120];

  for (int u = t; u < 16 * 256; u += 256) {
    int pl = u >> 8, c = u & 255;
    Yt[pl * PHST + c] = y[(b * P_ + p0 + pl) * C_ + c];
  }
  __syncthreads();

  const int oA = t & 127, oB = oA + 128, pB = (t >> 7) * 8;
  float accA[8], accB[8];
  for (int l = 0; l < 2; l++) {
    const float* w = l ? pw2 : pw1;
    const float* inb = l ? Ht : Yt;
    float* outb = l ? Yt : Ht;
#pragma unroll
    for (int pp = 0; pp < 8; pp++) { accA[pp] = 0.f; accB[pp] = 0.f; }
    for (int tile = 0; tile < 16; tile++) {
      const int c0 = tile * 16;
      {
        const int orow = t >> 2, q = t & 3;
#pragma unroll
        for (int pass = 0; pass < 4; pass++) {
          int oo = orow + pass * 64;
          *(float4*)&Wt[oo * 20 + q * 4] =
              *(const float4*)(w + oo * 256 + c0 + q * 4);
        }
      }
      __syncthreads();
#pragma unroll
      for (int j4 = 0; j4 < 4; j4++) {
        const float4 wa = *(const float4*)&Wt[oA * 20 + j4 * 4];
        const float4 wb = *(const float4*)&Wt[oB * 20 + j4 * 4];
#pragma unroll
        for (int pp = 0; pp < 8; pp++) {
          const float4 xv =
              *(const float4*)&inb[(pB + pp) * PHST + c0 + j4 * 4];
          accA[pp] = fmaf(wa.x, xv.x, accA[pp]);
          accA[pp] = fmaf(wa.y, xv.y, accA[pp]);
          accA[pp] = fmaf(wa.z, xv.z, accA[pp]);
          accA[pp] = fmaf(wa.w, xv.w, accA[pp]);
          accB[pp] = fmaf(wb.x, xv.x, accB[pp]);
          accB[pp] = fmaf(wb.y, xv.y, accB[pp]);
          accB[pp] = fmaf(wb.z, xv.z, accB[pp]);
          accB[pp] = fmaf(wb.w, xv.w, accB[pp]);
        }
      }
      __syncthreads();
    }
    const float sA = pg[l * 256 + oA] / sqrtf(pv[l * 256 + oA] + 1e-5f);
    const float sB = pg[l * 256 + oB] / sqrtf(pv[l * 256 + oB] + 1e-5f);
    const float mA = pm[l * 256 + oA], mB = pm[l * 256 + oB];
    const float bA = pb[l * 256 + oA], bB = pb[l * 256 + oB];
#pragma unroll
    for (int pp = 0; pp < 8; pp++) {
      outb[(pB + pp) * PHST + oA] = fmaxf((accA[pp] - mA) * sA + bA, 0.f);
      outb[(pB + pp) * PHST + oB] = fmaxf((accB[pp] - mB) * sB + bB, 0.f);
    }
  }
  // final layer: 119 outputs, reads Yt
  {
    const int o = t & 127, ph = t >> 7;
    float a3[8];
#pragma unroll
    for (int pp = 0; pp < 8; pp++) a3[pp] = 0.f;
    for (int tile = 0; tile < 16; tile++) {
      const int c0 = tile * 16;
      for (int u = t; u < 119 * 4; u += 256) {
        int oo = u >> 2, q = u & 3;
        *(float4*)&Wt[oo * 20 + q * 4] =
            *(const float4*)(pw3 + oo * 256 + c0 + q * 4);
      }
      __syncthreads();
      if (o < 119) {
#pragma unroll
        for (int j4 = 0; j4 < 4; j4++) {
          const float4 wv = *(const float4*)&Wt[o * 20 + j4 * 4];
#pragma unroll
          for (int pp = 0; pp < 8; pp++) {
            const float4 xv =
                *(const float4*)&Yt[(ph * 8 + pp) * PHST + c0 + j4 * 4];
            a3[pp] = fmaf(wv.x, xv.x, a3[pp]);
            a3[pp] = fmaf(wv.y, xv.y, a3[pp]);
            a3[pp] = fmaf(wv.z, xv.z, a3[pp]);
            a3[pp] = fmaf(wv.w, xv.w, a3[pp]);
          }
        }
      }
      __syncthreads();
    }
    if (o < 119) {
      const float bb = pb3[o];
#pragma unroll
      for (int pp = 0; pp < 8; pp++) net_s[(ph * 8 + pp) * 120 + o] = a3[pp] + bb;
    }
  }
  __syncthreads();

  // heads: one thread per proposal
  if (t < 16) {
    const int pg_i = p0 + t;
    const int gi = b * P_ + pg_i;
    const float* nr = &net_s[t * 120];
    const float nx = new_xyz[gi * 3 + 0];
    const float ny = new_xyz[gi * 3 + 1];
    const float nz = new_xyz[gi * 3 + 2];
    const float obj0 = nr[0], obj1 = nr[1];
    out[OFF0 + gi * 2 + 0] = obj0;
    out[OFF0 + gi * 2 + 1] = obj1;
    const float cx = nx + nr[2], cy = ny + nr[3], cz = nz + nr[4];
    out[OFF1 + gi * 3 + 0] = cx;
    out[OFF1 + gi * 3 + 1] = cy;
    out[OFF1 + gi * 3 + 2] = cz;
    // size scores + argmax (first max)
    float bv = -1e30f;
    int bi = 0;
#pragma unroll
    for (int i = 0; i < 18; i++) {
      float v = nr[29 + i];
      out[OFF2 + gi * 18 + i] = v;
      if (v > bv) { bv = v; bi = i; }
    }
    // size residuals
#pragma unroll
    for (int i = 0; i < 18; i++)
#pragma unroll
      for (int j = 0; j < 3; j++)
        out[OFF3 + gi * 54 + i * 3 + j] =
            __fmul_rn(nr[47 + i * 3 + j], msa[i * 3 + j]);
    float ps[3];
#pragma unroll
    for (int j = 0; j < 3; j++) {
      ps[j] = __fadd_rn(__fmul_rn(nr[47 + bi * 3 + j], msa[bi * 3 + j]),
                        msa[bi * 3 + j]);
      out[OFF4 + gi * 3 + j] = ps[j];
    }
    // sem + sem_logits + softmaxes
    float sm = -1e30f;
#pragma unroll
    for (int i = 0; i < 18; i++) {
      float v = nr[101 + i];
      out[OFF5 + gi * 18 + i] = v;
      out[OFF7 + gi * 19 + i] = v;
      sm = fmaxf(sm, v);
    }
    out[OFF7 + gi * 19 + 18] = (obj0 <= obj1) ? 0.f : 1e10f;
    // corners (angle = 0 -> R = I)
    const float cc0 = cx, cc1 = cz, cc2 = -cy;
    const float sxk[8] = {1, 1, -1, -1, 1, 1, -1, -1};
    const float syk[8] = {1, 1, 1, 1, -1, -1, -1, -1};
    const float szk[8] = {1, -1, -1, 1, 1, -1, -1, 1};
#pragma unroll
    for (int k = 0; k < 8; k++) {
      out[OFF6 + gi * 24 + 3 * k + 0] = cc0 + ps[0] * sxk[k] * 0.5f;
      out[OFF6 + gi * 24 + 3 * k + 1] = cc1 + ps[2] * syk[k] * 0.5f;
      out[OFF6 + gi * 24 + 3 * k + 2] = cc2 + ps[1] * szk[k] * 0.5f;
    }
    // obj softmax prob of class 1
    {
      const float m2 = fmaxf(obj0, obj1);
      const float e0 = expf(obj0 - m2), e1 = expf(obj1 - m2);
      out[OFF8 + gi] = e1 / (e0 + e1);
    }
    // sem softmax
    {
      float ev[18], es = 0.f;
#pragma unroll
      for (int i = 0; i < 18; i++) {
        ev[i] = expf(nr[101 + i] - sm);
        es += ev[i];
      }
#pragma unroll
      for (int i = 0; i < 18; i++) out[OFF9 + gi * 18 + i] = ev[i] / es;
    }
  }
}

// ---------------------------------------------------------------------------
extern "C" void kernel_launch(void* const* d_in, const int* in_sizes, int n_in,
                              void* d_out, int out_size, void* d_ws,
                              size_t ws_size, hipStream_t stream) {
  (void)in_sizes; (void)n_in; (void)out_size; (void)ws_size;
  const float* xyz      = (const float*)d_in[0];
  const float* features = (const float*)d_in[1];
  const float* w1       = (const float*)d_in[2];
  const float* w2       = (const float*)d_in[3];
  const float* w3       = (const float*)d_in[4];
  const float* gma      = (const float*)d_in[5];
  const float* bta      = (const float*)d_in[6];
  const float* mu       = (const float*)d_in[7];
  const float* var      = (const float*)d_in[8];
  const float* pw1      = (const float*)d_in[9];
  const float* pw2      = (const float*)d_in[10];
  const float* pw3      = (const float*)d_in[11];
  const float* pb3      = (const float*)d_in[12];
  const float* pg       = (const float*)d_in[13];
  const float* pb       = (const float*)d_in[14];
  const float* pm       = (const float*)d_in[15];
  const float* pv       = (const float*)d_in[16];
  const float* msa      = (const float*)d_in[17];
  float* out = (float*)d_out;

  char* ws = (char*)d_ws;
  float* new_xyz = (float*)ws;                  // 32*256*3 f   = 98304 B
  int*   idxw    = (int*)(ws + 98304);          // 32*256*16 i  = 524288 B
  float* yb      = (float*)(ws + 622592);       // 32*256*256 f = 8388608 B

  fps_kernel<<<B_, 256, 0, stream>>>(xyz, new_xyz);
  ballq_kernel<<<B_, 256, 0, stream>>>(xyz, new_xyz, idxw);
  sa_kernel<<<B_ * P_, 256, 0, stream>>>(xyz, features, w1, w2, w3, gma, bta,
                                         mu, var, new_xyz, idxw, yb);
  phead_kernel<<<B_ * 16, 256, 0, stream>>>(yb, pw1, pw2, pw3, pb3, pg, pb, pm,
                                            pv, new_xyz, msa, out);
}

// Round 2
// 1878.606 us; speedup vs baseline: 1.3021x; 1.3021x over previous
//
#include <hip/hip_runtime.h>
#include <math.h>

#define B_   32
#define K_   2048
#define C_   256
#define P_   256
#define S_   16
#define OUTC 119

// output offsets (floats)
#define OFF0 0        // obj        (B,P,2)
#define OFF1 16384    // center     (B,P,3)
#define OFF2 40960    // size_scores(B,P,18)
#define OFF3 188416   // size_res   (B,P,18,3)
#define OFF4 630784   // pred_size  (B,P,3)
#define OFF5 655360   // sem        (B,P,18)
#define OFF6 802816   // corners    (B,P,8,3)
#define OFF7 999424   // sem_logits (B,P,19)
#define OFF8 1155072  // obj_prob   (B,P)
#define OFF9 1163264  // sem_prob   (B,P,18)

__device__ __forceinline__ float sqdist_rn(float ax, float ay, float az,
                                           float bx, float by, float bz) {
  // numpy order: ((dx*dx + dy*dy) + dz*dz), no FMA contraction
  float dx = __fsub_rn(ax, bx), dy = __fsub_rn(ay, by), dz = __fsub_rn(az, bz);
  return __fadd_rn(__fadd_rn(__fmul_rn(dx, dx), __fmul_rn(dy, dy)),
                   __fmul_rn(dz, dz));
}

// ---------------------------------------------------------------- FPS ------
__global__ __launch_bounds__(256) void fps_kernel(const float* __restrict__ xyz,
                                                  float* __restrict__ new_xyz) {
  const int b = blockIdx.x, t = threadIdx.x;
  const float* xb = xyz + b * K_ * 3;
  float px[8], py[8], pz[8], dist[8];
#pragma unroll
  for (int j = 0; j < 8; j++) {
    int k = t + 256 * j;
    px[j] = xb[3 * k + 0];
    py[j] = xb[3 * k + 1];
    pz[j] = xb[3 * k + 2];
    dist[j] = 1e10f;
  }
  __shared__ float s_val[4];
  __shared__ int s_idx[4];
  __shared__ int s_far;
  int far = 0;
  for (int i = 0; i < P_; i++) {
    float cx = xb[3 * far + 0], cy = xb[3 * far + 1], cz = xb[3 * far + 2];
    if (t == 0) {
      float* nx = new_xyz + (b * P_ + i) * 3;
      nx[0] = cx; nx[1] = cy; nx[2] = cz;
    }
    float bv = -1.0f;
    int bk = 0x7fffffff;
#pragma unroll
    for (int j = 0; j < 8; j++) {
      float d = sqdist_rn(px[j], py[j], pz[j], cx, cy, cz);
      dist[j] = fminf(dist[j], d);
      int k = t + 256 * j;
      if (dist[j] > bv || (dist[j] == bv && k < bk)) { bv = dist[j]; bk = k; }
    }
#pragma unroll
    for (int off = 32; off >= 1; off >>= 1) {
      float ov = __shfl_down(bv, off);
      int ok = __shfl_down(bk, off);
      if (ov > bv || (ov == bv && ok < bk)) { bv = ov; bk = ok; }
    }
    if ((t & 63) == 0) { s_val[t >> 6] = bv; s_idx[t >> 6] = bk; }
    __syncthreads();
    if (t == 0) {
      for (int w = 1; w < 4; w++) {
        float ov = s_val[w]; int ok = s_idx[w];
        if (ov > bv || (ov == bv && ok < bk)) { bv = ov; bk = ok; }
      }
      s_far = bk;
    }
    __syncthreads();
    far = s_far;
  }
}

// ---------------------------------------------------------- ball query -----
__global__ __launch_bounds__(256) void ballq_kernel(const float* __restrict__ xyz,
                                                    const float* __restrict__ new_xyz,
                                                    int* __restrict__ idxw) {
  const int b = blockIdx.x, t = threadIdx.x;
  __shared__ __align__(16) float pts[K_ * 4];
  const float* xb = xyz + b * K_ * 3;
#pragma unroll
  for (int j = 0; j < 8; j++) {
    int k = t + 256 * j;
    pts[4 * k + 0] = xb[3 * k + 0];
    pts[4 * k + 1] = xb[3 * k + 1];
    pts[4 * k + 2] = xb[3 * k + 2];
    pts[4 * k + 3] = 0.f;
  }
  __syncthreads();
  const float r2 = (float)(0.3 * 0.3);
  const int p = t;
  const float nx = new_xyz[(b * P_ + p) * 3 + 0];
  const float ny = new_xyz[(b * P_ + p) * 3 + 1];
  const float nz = new_xyz[(b * P_ + p) * 3 + 2];
  int* ob = idxw + (b * P_ + p) * S_;
  int cnt = 0, first = 0;
  for (int k = 0; k < K_; k++) {
    if (cnt >= S_) break;
    const float4 q = *(const float4*)&pts[4 * k];
    float d2 = sqdist_rn(q.x, q.y, q.z, nx, ny, nz);
    if (d2 < r2) {
      if (cnt == 0) first = k;
      ob[cnt] = k;
      cnt++;
    }
  }
  for (int s = cnt; s < S_; s++) ob[s] = first;
}

// ------------------------------------------------------------- SA MLP ------
// One block per 2 proposals (32 samples). X kept c-major [c][32] in LDS so
// x-reads are wave-uniform (broadcast, conflict-free). Weights staged
// transposed Wc[c][o] so w-reads are lane-contiguous b128 (conflict-free).
// Thread = 4 outputs x 8 samples = 32 accumulators; per 8-c chunk:
// 24 ds_read_b128 vs 256 FMAs -> FMA-issue bound.
#define KPAD1 264
__global__ __launch_bounds__(256, 2) void sa_kernel(
    const float* __restrict__ xyz, const float* __restrict__ features,
    const float* __restrict__ w1, const float* __restrict__ w2,
    const float* __restrict__ w3, const float* __restrict__ gma,
    const float* __restrict__ bta, const float* __restrict__ mu,
    const float* __restrict__ var, const float* __restrict__ new_xyz,
    const int* __restrict__ idxw, float* __restrict__ y) {
  const int blk = blockIdx.x;                 // 4096 blocks
  const int b = blk >> 7, p0 = (blk & 127) * 2, t = threadIdx.x;
  __shared__ __align__(16) float XA[KPAD1 * 32];  // 33792 B (layer0 in, layer1 out)
  __shared__ __align__(16) float XB[256 * 32];    // 32768 B (layer0 out, layer1 in)
  __shared__ __align__(16) float Wc[8 * 256];     // 8192 B  (transposed w chunk)
  __shared__ __align__(16) float red[4 * 256];    // 4096 B  (maxpool partials)
  __shared__ int k_sh[32];

  // ---- gather ----
  if (t < 32) k_sh[t] = idxw[(b * P_ + p0) * S_ + t];
  if (t < 160) XA[259 * 32 + t] = 0.f;  // zero pad rows 259..263
  __syncthreads();
  if (t < 32) {
    const int pl = t >> 4;
    const int k = k_sh[t];
    const float* xb = xyz + b * K_ * 3;
    const float* nx = new_xyz + (b * P_ + p0 + pl) * 3;
    XA[0 * 32 + t] = (xb[3 * k + 0] - nx[0]) / 0.3f;
    XA[1 * 32 + t] = (xb[3 * k + 1] - nx[1]) / 0.3f;
    XA[2 * 32 + t] = (xb[3 * k + 2] - nx[2]) / 0.3f;
  }
  {
    // features row c = t; swizzled s order to avoid same-bank writes
    const float* fb = features + (size_t)b * C_ * K_ + (size_t)t * K_;
    const int tw = t & 31;
#pragma unroll 8
    for (int si = 0; si < 32; si++) {
      const int s = (si + tw) & 31;
      XA[(3 + t) * 32 + s] = fb[k_sh[s]];
    }
  }

  const int og = t & 63;   // outputs 4*og .. 4*og+3
  const int sg = t >> 6;   // samples 8*sg .. 8*sg+7 (wave-uniform)
  const int o4 = og * 4;
  const int s8 = sg * 8;

  float acc[4][8];

  for (int l = 0; l < 3; l++) {
    const float* w = (l == 0) ? w1 : ((l == 1) ? w2 : w3);
    const float* Xin = (l == 1) ? XB : XA;
    float* Xout = (l == 0) ? XB : XA;
    const int nch = (l == 0) ? 33 : 32;
#pragma unroll
    for (int i = 0; i < 4; i++)
#pragma unroll
      for (int j = 0; j < 8; j++) acc[i][j] = 0.f;

    for (int ch = 0; ch < nch; ch++) {
      const int c0 = ch * 8;
      __syncthreads();  // protect Wc reuse; makes prior X writes visible
      if (l == 0) {
#pragma unroll
        for (int j = 0; j < 8; j++) {
          const int c = c0 + j;
          Wc[j * 256 + t] = (c < 259) ? w[t * 259 + c] : 0.f;
        }
      } else {
        const float4 a0 = *(const float4*)(w + t * 256 + c0);
        const float4 a1 = *(const float4*)(w + t * 256 + c0 + 4);
        Wc[0 * 256 + t] = a0.x; Wc[1 * 256 + t] = a0.y;
        Wc[2 * 256 + t] = a0.z; Wc[3 * 256 + t] = a0.w;
        Wc[4 * 256 + t] = a1.x; Wc[5 * 256 + t] = a1.y;
        Wc[6 * 256 + t] = a1.z; Wc[7 * 256 + t] = a1.w;
      }
      __syncthreads();
#pragma unroll
      for (int j = 0; j < 8; j++) {
        const int c = c0 + j;
        const float4 wf = *(const float4*)&Wc[j * 256 + o4];
        const float4 x0 = *(const float4*)&Xin[c * 32 + s8];
        const float4 x1 = *(const float4*)&Xin[c * 32 + s8 + 4];
        const float wv[4] = {wf.x, wf.y, wf.z, wf.w};
        const float xs[8] = {x0.x, x0.y, x0.z, x0.w, x1.x, x1.y, x1.z, x1.w};
#pragma unroll
        for (int i = 0; i < 4; i++)
#pragma unroll
          for (int jj = 0; jj < 8; jj++)
            acc[i][jj] = fmaf(wv[i], xs[jj], acc[i][jj]);
      }
    }

    if (l < 2) {
      const float4 g4 = *(const float4*)&gma[l * 256 + o4];
      const float4 v4 = *(const float4*)&var[l * 256 + o4];
      const float4 m4 = *(const float4*)&mu[l * 256 + o4];
      const float4 b4 = *(const float4*)&bta[l * 256 + o4];
      const float sc[4] = {g4.x / sqrtf(v4.x + 1e-5f), g4.y / sqrtf(v4.y + 1e-5f),
                           g4.z / sqrtf(v4.z + 1e-5f), g4.w / sqrtf(v4.w + 1e-5f)};
      const float mm[4] = {m4.x, m4.y, m4.z, m4.w};
      const float bb[4] = {b4.x, b4.y, b4.z, b4.w};
#pragma unroll
      for (int i = 0; i < 4; i++) {
        float4 r0, r1;
        r0.x = fmaxf((acc[i][0] - mm[i]) * sc[i] + bb[i], 0.f);
        r0.y = fmaxf((acc[i][1] - mm[i]) * sc[i] + bb[i], 0.f);
        r0.z = fmaxf((acc[i][2] - mm[i]) * sc[i] + bb[i], 0.f);
        r0.w = fmaxf((acc[i][3] - mm[i]) * sc[i] + bb[i], 0.f);
        r1.x = fmaxf((acc[i][4] - mm[i]) * sc[i] + bb[i], 0.f);
        r1.y = fmaxf((acc[i][5] - mm[i]) * sc[i] + bb[i], 0.f);
        r1.z = fmaxf((acc[i][6] - mm[i]) * sc[i] + bb[i], 0.f);
        r1.w = fmaxf((acc[i][7] - mm[i]) * sc[i] + bb[i], 0.f);
        *(float4*)&Xout[(o4 + i) * 32 + s8] = r0;
        *(float4*)&Xout[(o4 + i) * 32 + s8 + 4] = r1;
      }
    } else {
      // maxpool over this thread's 8 samples (all one proposal: 16 | 8*sg)
      float4 r;
      float rr[4];
#pragma unroll
      for (int i = 0; i < 4; i++) {
        float m = acc[i][0];
#pragma unroll
        for (int j = 1; j < 8; j++) m = fmaxf(m, acc[i][j]);
        rr[i] = m;
      }
      r.x = rr[0]; r.y = rr[1]; r.z = rr[2]; r.w = rr[3];
      *(float4*)&red[sg * 256 + o4] = r;
      __syncthreads();
      // final: thread t = output channel, both proposals
      const float sc2 = gma[512 + t] / sqrtf(var[512 + t] + 1e-5f);
      const float mu2 = mu[512 + t], bt2 = bta[512 + t];
#pragma unroll
      for (int pl = 0; pl < 2; pl++) {
        const float raw = fmaxf(red[(2 * pl) * 256 + t], red[(2 * pl + 1) * 256 + t]);
        y[(b * P_ + p0 + pl) * 256 + t] = fmaxf((raw - mu2) * sc2 + bt2, 0.f);
      }
    }
  }
}

// ------------------------------------------------- P-layers + all heads ----
#define PHST 260
__global__ __launch_bounds__(256, 2) void phead_kernel(
    const float* __restrict__ y, const float* __restrict__ pw1,
    const float* __restrict__ pw2, const float* __restrict__ pw3,
    const float* __restrict__ pb3, const float* __restrict__ pg,
    const float* __restrict__ pb, const float* __restrict__ pm,
    const float* __restrict__ pv, const float* __restrict__ new_xyz,
    const float* __restrict__ msa, float* __restrict__ out) {
  const int blk = blockIdx.x;
  const int b = blk >> 4, p0 = (blk & 15) * 16, t = threadIdx.x;
  __shared__ __align__(16) float Yt[16 * PHST];
  __shared__ __align__(16) float Ht[16 * PHST];
  __shared__ __align__(16) float Wt[256 * 20];
  __shared__ float net_s[16 * 120];

  for (int u = t; u < 16 * 256; u += 256) {
    int pl = u >> 8, c = u & 255;
    Yt[pl * PHST + c] = y[(b * P_ + p0 + pl) * C_ + c];
  }
  __syncthreads();

  const int oA = t & 127, oB = oA + 128, pB = (t >> 7) * 8;
  float accA[8], accB[8];
  for (int l = 0; l < 2; l++) {
    const float* w = l ? pw2 : pw1;
    const float* inb = l ? Ht : Yt;
    float* outb = l ? Yt : Ht;
#pragma unroll
    for (int pp = 0; pp < 8; pp++) { accA[pp] = 0.f; accB[pp] = 0.f; }
    for (int tile = 0; tile < 16; tile++) {
      const int c0 = tile * 16;
      {
        const int orow = t >> 2, q = t & 3;
#pragma unroll
        for (int pass = 0; pass < 4; pass++) {
          int oo = orow + pass * 64;
          *(float4*)&Wt[oo * 20 + q * 4] =
              *(const float4*)(w + oo * 256 + c0 + q * 4);
        }
      }
      __syncthreads();
#pragma unroll
      for (int j4 = 0; j4 < 4; j4++) {
        const float4 wa = *(const float4*)&Wt[oA * 20 + j4 * 4];
        const float4 wb = *(const float4*)&Wt[oB * 20 + j4 * 4];
#pragma unroll
        for (int pp = 0; pp < 8; pp++) {
          const float4 xv =
              *(const float4*)&inb[(pB + pp) * PHST + c0 + j4 * 4];
          accA[pp] = fmaf(wa.x, xv.x, accA[pp]);
          accA[pp] = fmaf(wa.y, xv.y, accA[pp]);
          accA[pp] = fmaf(wa.z, xv.z, accA[pp]);
          accA[pp] = fmaf(wa.w, xv.w, accA[pp]);
          accB[pp] = fmaf(wb.x, xv.x, accB[pp]);
          accB[pp] = fmaf(wb.y, xv.y, accB[pp]);
          accB[pp] = fmaf(wb.z, xv.z, accB[pp]);
          accB[pp] = fmaf(wb.w, xv.w, accB[pp]);
        }
      }
      __syncthreads();
    }
    const float sA = pg[l * 256 + oA] / sqrtf(pv[l * 256 + oA] + 1e-5f);
    const float sB = pg[l * 256 + oB] / sqrtf(pv[l * 256 + oB] + 1e-5f);
    const float mA = pm[l * 256 + oA], mB = pm[l * 256 + oB];
    const float bA = pb[l * 256 + oA], bB = pb[l * 256 + oB];
#pragma unroll
    for (int pp = 0; pp < 8; pp++) {
      outb[(pB + pp) * PHST + oA] = fmaxf((accA[pp] - mA) * sA + bA, 0.f);
      outb[(pB + pp) * PHST + oB] = fmaxf((accB[pp] - mB) * sB + bB, 0.f);
    }
  }
  // final layer: 119 outputs, reads Yt
  {
    const int o = t & 127, ph = t >> 7;
    float a3[8];
#pragma unroll
    for (int pp = 0; pp < 8; pp++) a3[pp] = 0.f;
    for (int tile = 0; tile < 16; tile++) {
      const int c0 = tile * 16;
      for (int u = t; u < 119 * 4; u += 256) {
        int oo = u >> 2, q = u & 3;
        *(float4*)&Wt[oo * 20 + q * 4] =
            *(const float4*)(pw3 + oo * 256 + c0 + q * 4);
      }
      __syncthreads();
      if (o < 119) {
#pragma unroll
        for (int j4 = 0; j4 < 4; j4++) {
          const float4 wv = *(const float4*)&Wt[o * 20 + j4 * 4];
#pragma unroll
          for (int pp = 0; pp < 8; pp++) {
            const float4 xv =
                *(const float4*)&Yt[(ph * 8 + pp) * PHST + c0 + j4 * 4];
            a3[pp] = fmaf(wv.x, xv.x, a3[pp]);
            a3[pp] = fmaf(wv.y, xv.y, a3[pp]);
            a3[pp] = fmaf(wv.z, xv.z, a3[pp]);
            a3[pp] = fmaf(wv.w, xv.w, a3[pp]);
          }
        }
      }
      __syncthreads();
    }
    if (o < 119) {
      const float bb = pb3[o];
#pragma unroll
      for (int pp = 0; pp < 8; pp++) net_s[(ph * 8 + pp) * 120 + o] = a3[pp] + bb;
    }
  }
  __syncthreads();

  // heads: one thread per proposal
  if (t < 16) {
    const int pg_i = p0 + t;
    const int gi = b * P_ + pg_i;
    const float* nr = &net_s[t * 120];
    const float nx = new_xyz[gi * 3 + 0];
    const float ny = new_xyz[gi * 3 + 1];
    const float nz = new_xyz[gi * 3 + 2];
    const float obj0 = nr[0], obj1 = nr[1];
    out[OFF0 + gi * 2 + 0] = obj0;
    out[OFF0 + gi * 2 + 1] = obj1;
    const float cx = nx + nr[2], cy = ny + nr[3], cz = nz + nr[4];
    out[OFF1 + gi * 3 + 0] = cx;
    out[OFF1 + gi * 3 + 1] = cy;
    out[OFF1 + gi * 3 + 2] = cz;
    // size scores + argmax (first max)
    float bv = -1e30f;
    int bi = 0;
#pragma unroll
    for (int i = 0; i < 18; i++) {
      float v = nr[29 + i];
      out[OFF2 + gi * 18 + i] = v;
      if (v > bv) { bv = v; bi = i; }
    }
    // size residuals
#pragma unroll
    for (int i = 0; i < 18; i++)
#pragma unroll
      for (int j = 0; j < 3; j++)
        out[OFF3 + gi * 54 + i * 3 + j] =
            __fmul_rn(nr[47 + i * 3 + j], msa[i * 3 + j]);
    float ps[3];
#pragma unroll
    for (int j = 0; j < 3; j++) {
      ps[j] = __fadd_rn(__fmul_rn(nr[47 + bi * 3 + j], msa[bi * 3 + j]),
                        msa[bi * 3 + j]);
      out[OFF4 + gi * 3 + j] = ps[j];
    }
    // sem + sem_logits + softmaxes
    float sm = -1e30f;
#pragma unroll
    for (int i = 0; i < 18; i++) {
      float v = nr[101 + i];
      out[OFF5 + gi * 18 + i] = v;
      out[OFF7 + gi * 19 + i] = v;
      sm = fmaxf(sm, v);
    }
    out[OFF7 + gi * 19 + 18] = (obj0 <= obj1) ? 0.f : 1e10f;
    // corners (angle = 0 -> R = I)
    const float cc0 = cx, cc1 = cz, cc2 = -cy;
    const float sxk[8] = {1, 1, -1, -1, 1, 1, -1, -1};
    const float syk[8] = {1, 1, 1, 1, -1, -1, -1, -1};
    const float szk[8] = {1, -1, -1, 1, 1, -1, -1, 1};
#pragma unroll
    for (int k = 0; k < 8; k++) {
      out[OFF6 + gi * 24 + 3 * k + 0] = cc0 + ps[0] * sxk[k] * 0.5f;
      out[OFF6 + gi * 24 + 3 * k + 1] = cc1 + ps[2] * syk[k] * 0.5f;
      out[OFF6 + gi * 24 + 3 * k + 2] = cc2 + ps[1] * szk[k] * 0.5f;
    }
    // obj softmax prob of class 1
    {
      const float m2 = fmaxf(obj0, obj1);
      const float e0 = expf(obj0 - m2), e1 = expf(obj1 - m2);
      out[OFF8 + gi] = e1 / (e0 + e1);
    }
    // sem softmax
    {
      float ev[18], es = 0.f;
#pragma unroll
      for (int i = 0; i < 18; i++) {
        ev[i] = expf(nr[101 + i] - sm);
        es += ev[i];
      }
#pragma unroll
      for (int i = 0; i < 18; i++) out[OFF9 + gi * 18 + i] = ev[i] / es;
    }
  }
}

// ---------------------------------------------------------------------------
extern "C" void kernel_launch(void* const* d_in, const int* in_sizes, int n_in,
                              void* d_out, int out_size, void* d_ws,
                              size_t ws_size, hipStream_t stream) {
  (void)in_sizes; (void)n_in; (void)out_size; (void)ws_size;
  const float* xyz      = (const float*)d_in[0];
  const float* features = (const float*)d_in[1];
  const float* w1       = (const float*)d_in[2];
  const float* w2       = (const float*)d_in[3];
  const float* w3       = (const float*)d_in[4];
  const float* gma      = (const float*)d_in[5];
  const float* bta      = (const float*)d_in[6];
  const float* mu       = (const float*)d_in[7];
  const float* var      = (const float*)d_in[8];
  const float* pw1      = (const float*)d_in[9];
  const float* pw2      = (const float*)d_in[10];
  const float* pw3      = (const float*)d_in[11];
  const float* pb3      = (const float*)d_in[12];
  const float* pg       = (const float*)d_in[13];
  const float* pb       = (const float*)d_in[14];
  const float* pm       = (const float*)d_in[15];
  const float* pv       = (const float*)d_in[16];
  const float* msa      = (const float*)d_in[17];
  float* out = (float*)d_out;

  char* ws = (char*)d_ws;
  float* new_xyz = (float*)ws;                  // 32*256*3 f   = 98304 B
  int*   idxw    = (int*)(ws + 98304);          // 32*256*16 i  = 524288 B
  float* yb      = (float*)(ws + 622592);       // 32*256*256 f = 8388608 B

  fps_kernel<<<B_, 256, 0, stream>>>(xyz, new_xyz);
  ballq_kernel<<<B_, 256, 0, stream>>>(xyz, new_xyz, idxw);
  sa_kernel<<<B_ * 128, 256, 0, stream>>>(xyz, features, w1, w2, w3, gma, bta,
                                          mu, var, new_xyz, idxw, yb);
  phead_kernel<<<B_ * 16, 256, 0, stream>>>(yb, pw1, pw2, pw3, pb3, pg, pb, pm,
                                            pv, new_xyz, msa, out);
}

// Round 3
// 1375.391 us; speedup vs baseline: 1.7786x; 1.3659x over previous
//
#include <hip/hip_runtime.h>
#include <math.h>

#define B_   32
#define K_   2048
#define C_   256
#define P_   256
#define S_   16
#define OUTC 119

// output offsets (floats)
#define OFF0 0        // obj        (B,P,2)
#define OFF1 16384    // center     (B,P,3)
#define OFF2 40960    // size_scores(B,P,18)
#define OFF3 188416   // size_res   (B,P,18,3)
#define OFF4 630784   // pred_size  (B,P,3)
#define OFF5 655360   // sem        (B,P,18)
#define OFF6 802816   // corners    (B,P,8,3)
#define OFF7 999424   // sem_logits (B,P,19)
#define OFF8 1155072  // obj_prob   (B,P)
#define OFF9 1163264  // sem_prob   (B,P,18)

// transposed-weight workspace offsets (floats)
#define WT1_OFF 0         // 264 x 256 (rows 259..263 zero)
#define WT2_OFF 67584     // 256 x 256
#define WT3_OFF 133120    // 256 x 256
#define WT_FLOATS 198656

__device__ __forceinline__ float sqdist_rn(float ax, float ay, float az,
                                           float bx, float by, float bz) {
  // numpy order: ((dx*dx + dy*dy) + dz*dz), no FMA contraction
  float dx = __fsub_rn(ax, bx), dy = __fsub_rn(ay, by), dz = __fsub_rn(az, bz);
  return __fadd_rn(__fadd_rn(__fmul_rn(dx, dx), __fmul_rn(dy, dy)),
                   __fmul_rn(dz, dz));
}

// --------------------------------------------------- weight transpose ------
// wt[c][o] = w[o][c]; rows 259..263 of wt1 zero-filled.
__global__ __launch_bounds__(256) void wtrans_kernel(
    const float* __restrict__ w1, const float* __restrict__ w2,
    const float* __restrict__ w3, float* __restrict__ wt) {
  const int r = blockIdx.x, t = threadIdx.x;
  if (r < 264) {
    wt[WT1_OFF + r * 256 + t] = (r < 259) ? w1[t * 259 + r] : 0.f;
  } else if (r < 520) {
    const int c = r - 264;
    wt[WT2_OFF + c * 256 + t] = w2[t * 256 + c];
  } else {
    const int c = r - 520;
    wt[WT3_OFF + c * 256 + t] = w3[t * 256 + c];
  }
}

// ---------------------------------------------------------------- FPS ------
__global__ __launch_bounds__(256) void fps_kernel(const float* __restrict__ xyz,
                                                  float* __restrict__ new_xyz) {
  const int b = blockIdx.x, t = threadIdx.x;
  const float* xb = xyz + b * K_ * 3;
  __shared__ __align__(16) float pts[K_ * 4];
  float px[8], py[8], pz[8], dist[8];
#pragma unroll
  for (int j = 0; j < 8; j++) {
    int k = t + 256 * j;
    px[j] = xb[3 * k + 0];
    py[j] = xb[3 * k + 1];
    pz[j] = xb[3 * k + 2];
    dist[j] = 1e10f;
    pts[4 * k + 0] = px[j];
    pts[4 * k + 1] = py[j];
    pts[4 * k + 2] = pz[j];
    pts[4 * k + 3] = 0.f;
  }
  __shared__ float s_val[4];
  __shared__ int s_idx[4];
  __shared__ int s_far;
  int far = 0;
  __syncthreads();
  for (int i = 0; i < P_; i++) {
    // centroid from LDS (broadcast read, same values as global)
    const float cx = pts[4 * far + 0];
    const float cy = pts[4 * far + 1];
    const float cz = pts[4 * far + 2];
    if (t == 0) {
      float* nx = new_xyz + (b * P_ + i) * 3;
      nx[0] = cx; nx[1] = cy; nx[2] = cz;
    }
    float bv = -1.0f;
    int bk = 0x7fffffff;
#pragma unroll
    for (int j = 0; j < 8; j++) {
      float d = sqdist_rn(px[j], py[j], pz[j], cx, cy, cz);
      dist[j] = fminf(dist[j], d);
      int k = t + 256 * j;
      if (dist[j] > bv || (dist[j] == bv && k < bk)) { bv = dist[j]; bk = k; }
    }
#pragma unroll
    for (int off = 32; off >= 1; off >>= 1) {
      float ov = __shfl_down(bv, off);
      int ok = __shfl_down(bk, off);
      if (ov > bv || (ov == bv && ok < bk)) { bv = ov; bk = ok; }
    }
    if ((t & 63) == 0) { s_val[t >> 6] = bv; s_idx[t >> 6] = bk; }
    __syncthreads();
    if (t == 0) {
      for (int w = 1; w < 4; w++) {
        float ov = s_val[w]; int ok = s_idx[w];
        if (ov > bv || (ov == bv && ok < bk)) { bv = ov; bk = ok; }
      }
      s_far = bk;
    }
    __syncthreads();
    far = s_far;
  }
}

// ---------------------------------------------------------- ball query -----
__global__ __launch_bounds__(256) void ballq_kernel(const float* __restrict__ xyz,
                                                    const float* __restrict__ new_xyz,
                                                    int* __restrict__ idxw) {
  const int b = blockIdx.x, t = threadIdx.x;
  __shared__ __align__(16) float pts[K_ * 4];
  const float* xb = xyz + b * K_ * 3;
#pragma unroll
  for (int j = 0; j < 8; j++) {
    int k = t + 256 * j;
    pts[4 * k + 0] = xb[3 * k + 0];
    pts[4 * k + 1] = xb[3 * k + 1];
    pts[4 * k + 2] = xb[3 * k + 2];
    pts[4 * k + 3] = 0.f;
  }
  __syncthreads();
  const float r2 = (float)(0.3 * 0.3);
  const int p = t;
  const float nx = new_xyz[(b * P_ + p) * 3 + 0];
  const float ny = new_xyz[(b * P_ + p) * 3 + 1];
  const float nz = new_xyz[(b * P_ + p) * 3 + 2];
  int* ob = idxw + (b * P_ + p) * S_;
  int cnt = 0, first = 0;
  for (int k = 0; k < K_; k++) {
    if (cnt >= S_) break;
    const float4 q = *(const float4*)&pts[4 * k];
    float d2 = sqdist_rn(q.x, q.y, q.z, nx, ny, nz);
    if (d2 < r2) {
      if (cnt == 0) first = k;
      ob[cnt] = k;
      cnt++;
    }
  }
  for (int s = cnt; s < S_; s++) ob[s] = first;
}

// ------------------------------------------------------------- SA MLP ------
// One block per 2 proposals (32 samples). X c-major [c][32] (wave-uniform
// broadcast reads). Weights pre-transposed in ws: staging is 8 coalesced
// dword loads/thread/chunk, register-prefetched one chunk ahead so global
// latency hides under the 512-cycle FMA loop. Conflict-free ds_write (bank
// t%32) and conflict-free b128 weight reads in compute.
#define KPAD1 264
__global__ __launch_bounds__(256, 2) void sa_kernel(
    const float* __restrict__ xyz, const float* __restrict__ features,
    const float* __restrict__ wt, const float* __restrict__ gma,
    const float* __restrict__ bta, const float* __restrict__ mu,
    const float* __restrict__ var, const float* __restrict__ new_xyz,
    const int* __restrict__ idxw, float* __restrict__ y) {
  const int blk = blockIdx.x;                 // 4096 blocks
  const int b = blk >> 7, p0 = (blk & 127) * 2, t = threadIdx.x;
  __shared__ __align__(16) float XA[KPAD1 * 32];  // 33792 B
  __shared__ __align__(16) float XB[256 * 32];    // 32768 B
  __shared__ __align__(16) float Wc[8 * 256];     // 8192 B
  __shared__ __align__(16) float red[4 * 256];    // 4096 B
  __shared__ int k_sh[32];

  // ---- gather ----
  if (t < 32) k_sh[t] = idxw[(b * P_ + p0) * S_ + t];
  if (t < 160) XA[259 * 32 + t] = 0.f;  // zero pad rows 259..263
  __syncthreads();
  if (t < 32) {
    const int pl = t >> 4;
    const int k = k_sh[t];
    const float* xb = xyz + b * K_ * 3;
    const float* nx = new_xyz + (b * P_ + p0 + pl) * 3;
    XA[0 * 32 + t] = (xb[3 * k + 0] - nx[0]) / 0.3f;
    XA[1 * 32 + t] = (xb[3 * k + 1] - nx[1]) / 0.3f;
    XA[2 * 32 + t] = (xb[3 * k + 2] - nx[2]) / 0.3f;
  }
  {
    // features row c = t; swizzled s order to avoid same-bank writes
    const float* fb = features + (size_t)b * C_ * K_ + (size_t)t * K_;
    const int tw = t & 31;
#pragma unroll 8
    for (int si = 0; si < 32; si++) {
      const int s = (si + tw) & 31;
      XA[(3 + t) * 32 + s] = fb[k_sh[s]];
    }
  }

  const int og = t & 63;   // outputs 4*og .. 4*og+3
  const int sg = t >> 6;   // samples 8*sg .. 8*sg+7 (wave-uniform)
  const int o4 = og * 4;
  const int s8 = sg * 8;

  float acc[4][8];
  float wreg[8];
  // prefetch layer0 chunk0
#pragma unroll
  for (int j = 0; j < 8; j++) wreg[j] = wt[WT1_OFF + j * 256 + t];

  for (int l = 0; l < 3; l++) {
    const float* wtl =
        wt + ((l == 0) ? WT1_OFF : (l == 1) ? WT2_OFF : WT3_OFF);
    const float* wtnext = (l == 0) ? (wt + WT2_OFF) : (wt + WT3_OFF);
    const float* Xin = (l == 1) ? XB : XA;
    float* Xout = (l == 0) ? XB : XA;
    const int nch = (l == 0) ? 33 : 32;
#pragma unroll
    for (int i = 0; i < 4; i++)
#pragma unroll
      for (int j = 0; j < 8; j++) acc[i][j] = 0.f;

    for (int ch = 0; ch < nch; ch++) {
      const int c0 = ch * 8;
      __syncthreads();  // prior chunk's readers done / X writes visible
#pragma unroll
      for (int j = 0; j < 8; j++) Wc[j * 256 + t] = wreg[j];
      __syncthreads();  // Wc visible
      // prefetch next chunk (or next layer's chunk 0) into registers
      {
        const float* pn = (ch + 1 < nch) ? (wtl + (ch + 1) * 2048)
                                         : ((l < 2) ? wtnext : nullptr);
        if (pn) {
#pragma unroll
          for (int j = 0; j < 8; j++) wreg[j] = pn[j * 256 + t];
        }
      }
#pragma unroll
      for (int j = 0; j < 8; j++) {
        const int c = c0 + j;
        const float4 wf = *(const float4*)&Wc[j * 256 + o4];
        const float4 x0 = *(const float4*)&Xin[c * 32 + s8];
        const float4 x1 = *(const float4*)&Xin[c * 32 + s8 + 4];
        const float wv[4] = {wf.x, wf.y, wf.z, wf.w};
        const float xs[8] = {x0.x, x0.y, x0.z, x0.w, x1.x, x1.y, x1.z, x1.w};
#pragma unroll
        for (int i = 0; i < 4; i++)
#pragma unroll
          for (int jj = 0; jj < 8; jj++)
            acc[i][jj] = fmaf(wv[i], xs[jj], acc[i][jj]);
      }
    }

    if (l < 2) {
      const float4 g4 = *(const float4*)&gma[l * 256 + o4];
      const float4 v4 = *(const float4*)&var[l * 256 + o4];
      const float4 m4 = *(const float4*)&mu[l * 256 + o4];
      const float4 b4 = *(const float4*)&bta[l * 256 + o4];
      const float sc[4] = {g4.x / sqrtf(v4.x + 1e-5f), g4.y / sqrtf(v4.y + 1e-5f),
                           g4.z / sqrtf(v4.z + 1e-5f), g4.w / sqrtf(v4.w + 1e-5f)};
      const float mm[4] = {m4.x, m4.y, m4.z, m4.w};
      const float bb[4] = {b4.x, b4.y, b4.z, b4.w};
#pragma unroll
      for (int i = 0; i < 4; i++) {
        float4 r0, r1;
        r0.x = fmaxf((acc[i][0] - mm[i]) * sc[i] + bb[i], 0.f);
        r0.y = fmaxf((acc[i][1] - mm[i]) * sc[i] + bb[i], 0.f);
        r0.z = fmaxf((acc[i][2] - mm[i]) * sc[i] + bb[i], 0.f);
        r0.w = fmaxf((acc[i][3] - mm[i]) * sc[i] + bb[i], 0.f);
        r1.x = fmaxf((acc[i][4] - mm[i]) * sc[i] + bb[i], 0.f);
        r1.y = fmaxf((acc[i][5] - mm[i]) * sc[i] + bb[i], 0.f);
        r1.z = fmaxf((acc[i][6] - mm[i]) * sc[i] + bb[i], 0.f);
        r1.w = fmaxf((acc[i][7] - mm[i]) * sc[i] + bb[i], 0.f);
        *(float4*)&Xout[(o4 + i) * 32 + s8] = r0;
        *(float4*)&Xout[(o4 + i) * 32 + s8 + 4] = r1;
      }
    } else {
      // maxpool over this thread's 8 samples (one proposal each)
      float4 r;
      float rr[4];
#pragma unroll
      for (int i = 0; i < 4; i++) {
        float m = acc[i][0];
#pragma unroll
        for (int j = 1; j < 8; j++) m = fmaxf(m, acc[i][j]);
        rr[i] = m;
      }
      r.x = rr[0]; r.y = rr[1]; r.z = rr[2]; r.w = rr[3];
      *(float4*)&red[sg * 256 + o4] = r;
      __syncthreads();
      const float sc2 = gma[512 + t] / sqrtf(var[512 + t] + 1e-5f);
      const float mu2 = mu[512 + t], bt2 = bta[512 + t];
#pragma unroll
      for (int pl = 0; pl < 2; pl++) {
        const float raw = fmaxf(red[(2 * pl) * 256 + t], red[(2 * pl + 1) * 256 + t]);
        y[(b * P_ + p0 + pl) * 256 + t] = fmaxf((raw - mu2) * sc2 + bt2, 0.f);
      }
    }
  }
}

// ------------------------------------------------- P-layers + all heads ----
#define PHST 260
__global__ __launch_bounds__(256, 2) void phead_kernel(
    const float* __restrict__ y, const float* __restrict__ pw1,
    const float* __restrict__ pw2, const float* __restrict__ pw3,
    const float* __restrict__ pb3, const float* __restrict__ pg,
    const float* __restrict__ pb, const float* __restrict__ pm,
    const float* __restrict__ pv, const float* __restrict__ new_xyz,
    const float* __restrict__ msa, float* __restrict__ out) {
  const int blk = blockIdx.x;
  const int b = blk >> 4, p0 = (blk & 15) * 16, t = threadIdx.x;
  __shared__ __align__(16) float Yt[16 * PHST];
  __shared__ __align__(16) float Ht[16 * PHST];
  __shared__ __align__(16) float Wt[256 * 20];
  __shared__ float net_s[16 * 120];

  for (int u = t; u < 16 * 256; u += 256) {
    int pl = u >> 8, c = u & 255;
    Yt[pl * PHST + c] = y[(b * P_ + p0 + pl) * C_ + c];
  }
  __syncthreads();

  const int oA = t & 127, oB = oA + 128, pB = (t >> 7) * 8;
  float accA[8], accB[8];
  for (int l = 0; l < 2; l++) {
    const float* w = l ? pw2 : pw1;
    const float* inb = l ? Ht : Yt;
    float* outb = l ? Yt : Ht;
#pragma unroll
    for (int pp = 0; pp < 8; pp++) { accA[pp] = 0.f; accB[pp] = 0.f; }
    for (int tile = 0; tile < 16; tile++) {
      const int c0 = tile * 16;
      {
        const int orow = t >> 2, q = t & 3;
#pragma unroll
        for (int pass = 0; pass < 4; pass++) {
          int oo = orow + pass * 64;
          *(float4*)&Wt[oo * 20 + q * 4] =
              *(const float4*)(w + oo * 256 + c0 + q * 4);
        }
      }
      __syncthreads();
#pragma unroll
      for (int j4 = 0; j4 < 4; j4++) {
        const float4 wa = *(const float4*)&Wt[oA * 20 + j4 * 4];
        const float4 wb = *(const float4*)&Wt[oB * 20 + j4 * 4];
#pragma unroll
        for (int pp = 0; pp < 8; pp++) {
          const float4 xv =
              *(const float4*)&inb[(pB + pp) * PHST + c0 + j4 * 4];
          accA[pp] = fmaf(wa.x, xv.x, accA[pp]);
          accA[pp] = fmaf(wa.y, xv.y, accA[pp]);
          accA[pp] = fmaf(wa.z, xv.z, accA[pp]);
          accA[pp] = fmaf(wa.w, xv.w, accA[pp]);
          accB[pp] = fmaf(wb.x, xv.x, accB[pp]);
          accB[pp] = fmaf(wb.y, xv.y, accB[pp]);
          accB[pp] = fmaf(wb.z, xv.z, accB[pp]);
          accB[pp] = fmaf(wb.w, xv.w, accB[pp]);
        }
      }
      __syncthreads();
    }
    const float sA = pg[l * 256 + oA] / sqrtf(pv[l * 256 + oA] + 1e-5f);
    const float sB = pg[l * 256 + oB] / sqrtf(pv[l * 256 + oB] + 1e-5f);
    const float mA = pm[l * 256 + oA], mB = pm[l * 256 + oB];
    const float bA = pb[l * 256 + oA], bB = pb[l * 256 + oB];
#pragma unroll
    for (int pp = 0; pp < 8; pp++) {
      outb[(pB + pp) * PHST + oA] = fmaxf((accA[pp] - mA) * sA + bA, 0.f);
      outb[(pB + pp) * PHST + oB] = fmaxf((accB[pp] - mB) * sB + bB, 0.f);
    }
  }
  // final layer: 119 outputs, reads Yt
  {
    const int o = t & 127, ph = t >> 7;
    float a3[8];
#pragma unroll
    for (int pp = 0; pp < 8; pp++) a3[pp] = 0.f;
    for (int tile = 0; tile < 16; tile++) {
      const int c0 = tile * 16;
      for (int u = t; u < 119 * 4; u += 256) {
        int oo = u >> 2, q = u & 3;
        *(float4*)&Wt[oo * 20 + q * 4] =
            *(const float4*)(pw3 + oo * 256 + c0 + q * 4);
      }
      __syncthreads();
      if (o < 119) {
#pragma unroll
        for (int j4 = 0; j4 < 4; j4++) {
          const float4 wv = *(const float4*)&Wt[o * 20 + j4 * 4];
#pragma unroll
          for (int pp = 0; pp < 8; pp++) {
            const float4 xv =
                *(const float4*)&Yt[(ph * 8 + pp) * PHST + c0 + j4 * 4];
            a3[pp] = fmaf(wv.x, xv.x, a3[pp]);
            a3[pp] = fmaf(wv.y, xv.y, a3[pp]);
            a3[pp] = fmaf(wv.z, xv.z, a3[pp]);
            a3[pp] = fmaf(wv.w, xv.w, a3[pp]);
          }
        }
      }
      __syncthreads();
    }
    if (o < 119) {
      const float bb = pb3[o];
#pragma unroll
      for (int pp = 0; pp < 8; pp++) net_s[(ph * 8 + pp) * 120 + o] = a3[pp] + bb;
    }
  }
  __syncthreads();

  // heads: one thread per proposal
  if (t < 16) {
    const int pg_i = p0 + t;
    const int gi = b * P_ + pg_i;
    const float* nr = &net_s[t * 120];
    const float nx = new_xyz[gi * 3 + 0];
    const float ny = new_xyz[gi * 3 + 1];
    const float nz = new_xyz[gi * 3 + 2];
    const float obj0 = nr[0], obj1 = nr[1];
    out[OFF0 + gi * 2 + 0] = obj0;
    out[OFF0 + gi * 2 + 1] = obj1;
    const float cx = nx + nr[2], cy = ny + nr[3], cz = nz + nr[4];
    out[OFF1 + gi * 3 + 0] = cx;
    out[OFF1 + gi * 3 + 1] = cy;
    out[OFF1 + gi * 3 + 2] = cz;
    // size scores + argmax (first max)
    float bv = -1e30f;
    int bi = 0;
#pragma unroll
    for (int i = 0; i < 18; i++) {
      float v = nr[29 + i];
      out[OFF2 + gi * 18 + i] = v;
      if (v > bv) { bv = v; bi = i; }
    }
    // size residuals
#pragma unroll
    for (int i = 0; i < 18; i++)
#pragma unroll
      for (int j = 0; j < 3; j++)
        out[OFF3 + gi * 54 + i * 3 + j] =
            __fmul_rn(nr[47 + i * 3 + j], msa[i * 3 + j]);
    float ps[3];
#pragma unroll
    for (int j = 0; j < 3; j++) {
      ps[j] = __fadd_rn(__fmul_rn(nr[47 + bi * 3 + j], msa[bi * 3 + j]),
                        msa[bi * 3 + j]);
      out[OFF4 + gi * 3 + j] = ps[j];
    }
    // sem + sem_logits + softmaxes
    float sm = -1e30f;
#pragma unroll
    for (int i = 0; i < 18; i++) {
      float v = nr[101 + i];
      out[OFF5 + gi * 18 + i] = v;
      out[OFF7 + gi * 19 + i] = v;
      sm = fmaxf(sm, v);
    }
    out[OFF7 + gi * 19 + 18] = (obj0 <= obj1) ? 0.f : 1e10f;
    // corners (angle = 0 -> R = I)
    const float cc0 = cx, cc1 = cz, cc2 = -cy;
    const float sxk[8] = {1, 1, -1, -1, 1, 1, -1, -1};
    const float syk[8] = {1, 1, 1, 1, -1, -1, -1, -1};
    const float szk[8] = {1, -1, -1, 1, 1, -1, -1, 1};
#pragma unroll
    for (int k = 0; k < 8; k++) {
      out[OFF6 + gi * 24 + 3 * k + 0] = cc0 + ps[0] * sxk[k] * 0.5f;
      out[OFF6 + gi * 24 + 3 * k + 1] = cc1 + ps[2] * syk[k] * 0.5f;
      out[OFF6 + gi * 24 + 3 * k + 2] = cc2 + ps[1] * szk[k] * 0.5f;
    }
    // obj softmax prob of class 1
    {
      const float m2 = fmaxf(obj0, obj1);
      const float e0 = expf(obj0 - m2), e1 = expf(obj1 - m2);
      out[OFF8 + gi] = e1 / (e0 + e1);
    }
    // sem softmax
    {
      float ev[18], es = 0.f;
#pragma unroll
      for (int i = 0; i < 18; i++) {
        ev[i] = expf(nr[101 + i] - sm);
        es += ev[i];
      }
#pragma unroll
      for (int i = 0; i < 18; i++) out[OFF9 + gi * 18 + i] = ev[i] / es;
    }
  }
}

// ---------------------------------------------------------------------------
extern "C" void kernel_launch(void* const* d_in, const int* in_sizes, int n_in,
                              void* d_out, int out_size, void* d_ws,
                              size_t ws_size, hipStream_t stream) {
  (void)in_sizes; (void)n_in; (void)out_size; (void)ws_size;
  const float* xyz      = (const float*)d_in[0];
  const float* features = (const float*)d_in[1];
  const float* w1       = (const float*)d_in[2];
  const float* w2       = (const float*)d_in[3];
  const float* w3       = (const float*)d_in[4];
  const float* gma      = (const float*)d_in[5];
  const float* bta      = (const float*)d_in[6];
  const float* mu       = (const float*)d_in[7];
  const float* var      = (const float*)d_in[8];
  const float* pw1      = (const float*)d_in[9];
  const float* pw2      = (const float*)d_in[10];
  const float* pw3      = (const float*)d_in[11];
  const float* pb3      = (const float*)d_in[12];
  const float* pg       = (const float*)d_in[13];
  const float* pb       = (const float*)d_in[14];
  const float* pm       = (const float*)d_in[15];
  const float* pv       = (const float*)d_in[16];
  const float* msa      = (const float*)d_in[17];
  float* out = (float*)d_out;

  char* ws = (char*)d_ws;
  float* new_xyz = (float*)ws;                  // 32*256*3 f   = 98304 B
  int*   idxw    = (int*)(ws + 98304);          // 32*256*16 i  = 524288 B
  float* yb      = (float*)(ws + 622592);       // 32*256*256 f = 8388608 B
  float* wt      = (float*)(ws + 9011200);      // 198656 f     = 794624 B

  wtrans_kernel<<<776, 256, 0, stream>>>(w1, w2, w3, wt);
  fps_kernel<<<B_, 256, 0, stream>>>(xyz, new_xyz);
  ballq_kernel<<<B_, 256, 0, stream>>>(xyz, new_xyz, idxw);
  sa_kernel<<<B_ * 128, 256, 0, stream>>>(xyz, features, wt, gma, bta,
                                          mu, var, new_xyz, idxw, yb);
  phead_kernel<<<B_ * 16, 256, 0, stream>>>(yb, pw1, pw2, pw3, pb3, pg, pb, pm,
                                            pv, new_xyz, msa, out);
}